// Round 1
// 525.298 us; speedup vs baseline: 1.2167x; 1.2167x over previous
//
#include <hip/hip_runtime.h>
#include <hip/hip_bf16.h>
#include <stdint.h>
#include <stddef.h>

// LoRALinear: M=B*S=8192, K=IN_F=4096, N=OUT_F=4096, RANK=16, SCALING=2
// R3: main GEMM rewritten to the 256^2 8-phase template (T1+T2+T3+T4+T5):
//   - BK=64, 512 threads (8 waves 2Mx4N), 128 KiB LDS double-buffer
//   - raw s_barrier (no __syncthreads -> no compiler vmcnt(0) drain)
//   - counted s_waitcnt vmcnt(6) only at phases 4/8
//   - LDS slot swizzle ps = slot ^ (row&7), applied via pre-swizzled global
//     source (global_load_lds dest stays linear) -> conflict-free ds_read_b128
#define M_TOT 8192
#define K_TOT 4096
#define N_TOT 4096
#define RANK  16
#define SCALING 2.0f

typedef short bf16x8 __attribute__((ext_vector_type(8)));
typedef float f32x4  __attribute__((ext_vector_type(4)));

#define MFMA_16x16x32(a, b, c) __builtin_amdgcn_mfma_f32_16x16x32_bf16((a), (b), (c), 0, 0, 0)

__device__ __forceinline__ void async_copy16(void* lds, const void* g) {
    __builtin_amdgcn_global_load_lds(
        (const __attribute__((address_space(1))) uint32_t*)g,
        (__attribute__((address_space(3))) uint32_t*)lds,
        16, 0, 0);
}

// ---------------------------------------------------------------------------
// One-shot conversion of all four fp32 inputs to bf16 (unchanged).
// ---------------------------------------------------------------------------
#define NXC (M_TOT * K_TOT / 8)
#define NWC (N_TOT * K_TOT / 8)
#define NAC (RANK * K_TOT / 8)
#define NBC (N_TOT * RANK / 8)
#define NTOTC (NXC + NWC + NAC + NBC)

__global__ __launch_bounds__(256) void cvt_all_kernel(
    const float* __restrict__ x, const float* __restrict__ w,
    const float* __restrict__ a, const float* __restrict__ b,
    __hip_bfloat16* __restrict__ xb, __hip_bfloat16* __restrict__ wb,
    __hip_bfloat16* __restrict__ ab, __hip_bfloat16* __restrict__ bb)
{
    for (int c = blockIdx.x * 256 + threadIdx.x; c < NTOTC; c += gridDim.x * 256) {
        const float* s; __hip_bfloat16* d; int off;
        if (c < NXC)                  { s = x; d = xb; off = c; }
        else if (c < NXC + NWC)       { s = w; d = wb; off = c - NXC; }
        else if (c < NXC + NWC + NAC) { s = a; d = ab; off = c - NXC - NWC; }
        else                          { s = b; d = bb; off = c - NXC - NWC - NAC; }
        size_t i = (size_t)off * 8;
        float4 p = *(const float4*)(s + i);
        float4 q = *(const float4*)(s + i + 4);
        union { bf16x8 v; __hip_bfloat16 h[8]; } u;
        u.h[0] = __float2bfloat16(p.x); u.h[1] = __float2bfloat16(p.y);
        u.h[2] = __float2bfloat16(p.z); u.h[3] = __float2bfloat16(p.w);
        u.h[4] = __float2bfloat16(q.x); u.h[5] = __float2bfloat16(q.y);
        u.h[6] = __float2bfloat16(q.z); u.h[7] = __float2bfloat16(q.w);
        *(bf16x8*)(d + i) = u.v;
    }
}

// ---------------------------------------------------------------------------
// T[m][r] = SCALING * sum_k X[m][k]*loraA[r][k]  (unchanged)
// ---------------------------------------------------------------------------
__global__ __launch_bounds__(256) void lora_t_kernel(
    const __hip_bfloat16* __restrict__ X,
    const __hip_bfloat16* __restrict__ loraA,
    __hip_bfloat16* __restrict__ T)
{
    __shared__ float red[4][256];
    const int lane = threadIdx.x & 63;
    const int wid  = threadIdx.x >> 6;
    const int m0   = blockIdx.x * 16;
    const int lrow = lane & 15;
    const int lk   = lane >> 4;
    const int kofs = wid * (K_TOT / 4);

    f32x4 acc = {};
    const __hip_bfloat16* xp = X + (size_t)(m0 + lrow) * K_TOT + kofs + lk * 8;
    const __hip_bfloat16* ap = loraA + (size_t)lrow * K_TOT + kofs + lk * 8;

#pragma unroll 4
    for (int k0 = 0; k0 < K_TOT / 4; k0 += 32) {
        bf16x8 av = *(const bf16x8*)xp;
        bf16x8 bv = *(const bf16x8*)ap;
        xp += 32; ap += 32;
        acc = MFMA_16x16x32(av, bv, acc);
    }
#pragma unroll
    for (int r = 0; r < 4; r++)
        red[wid][(lk * 4 + r) * 16 + lrow] = acc[r];
    __syncthreads();

    const int t = threadIdx.x;
    float s = red[0][t] + red[1][t] + red[2][t] + red[3][t];
    T[(size_t)(m0 + (t >> 4)) * RANK + (t & 15)] = __float2bfloat16(SCALING * s);
}

// ---------------------------------------------------------------------------
// 8-phase 256x256 GEMM + fused scale/LoRA epilogue.
// out[m][n] = (sum_k X[m][k]*W[n][k])*scale[n] + sum_r T[m][r]*loraB[n][r]
// ---------------------------------------------------------------------------
#define BAR()    asm volatile("s_barrier" ::: "memory")
#define WAITV(N) asm volatile("s_waitcnt vmcnt(" #N ")" ::: "memory")
#define WAITL()  asm volatile("s_waitcnt lgkmcnt(0)" ::: "memory")

// read A fragments for quadrant QI: 4 m-frags x 2 k-steps (8 ds_read_b128)
#define READ_A(BASE, QI, DST) do {                                             \
    const char* _b = (BASE) + (wr * 128 + (QI) * 64 + lrow) * 128;             \
    _Pragma("unroll")                                                          \
    for (int mf = 0; mf < 4; mf++) {                                           \
        DST[mf][0] = *(const bf16x8*)(_b + mf * 2048 + ps_k0 * 16);            \
        DST[mf][1] = *(const bf16x8*)(_b + mf * 2048 + ps_k1 * 16);            \
    }                                                                          \
} while (0)

// read B fragments for quadrant QJ: 2 n-frags x 2 k-steps (4 ds_read_b128)
#define READ_B(BASE, QJ, DST) do {                                             \
    const char* _b = (BASE) + (wc * 64 + (QJ) * 32 + lrow) * 128;              \
    _Pragma("unroll")                                                          \
    for (int nf = 0; nf < 2; nf++) {                                           \
        DST[nf][0] = *(const bf16x8*)(_b + nf * 2048 + ps_k0 * 16);            \
        DST[nf][1] = *(const bf16x8*)(_b + nf * 2048 + ps_k1 * 16);            \
    }                                                                          \
} while (0)

// one C-quadrant x K=64: 16 MFMA, setprio-wrapped (T5)
#define MFMA16(QI, QJ, AF, BF) do {                                            \
    __builtin_amdgcn_s_setprio(1);                                             \
    _Pragma("unroll")                                                          \
    for (int mf = 0; mf < 4; mf++)                                             \
        _Pragma("unroll")                                                      \
        for (int nf = 0; nf < 2; nf++) {                                       \
            acc[QI][QJ][mf][nf] =                                              \
                MFMA_16x16x32(AF[mf][0], BF[nf][0], acc[QI][QJ][mf][nf]);      \
            acc[QI][QJ][mf][nf] =                                              \
                MFMA_16x16x32(AF[mf][1], BF[nf][1], acc[QI][QJ][mf][nf]);      \
        }                                                                      \
    __builtin_amdgcn_s_setprio(0);                                             \
} while (0)

// stage one A half-tile (H=0: rows 0-63 & 128-191; H=1: +64). 2 gload_lds.
// LDS dest linear; global source pre-swizzled: slot_log = ps ^ (row&7).
#define STAGE_A(H, LDSA, KOFF) do {                                            \
    int _r = rA + (H) * 64;                                                    \
    async_copy16((LDSA) + _r * 128 + ps * 16,                                  \
                 GA + (size_t)_r * K_TOT + (KOFF) + sl * 8);                   \
    async_copy16((LDSA) + _r * 128 + 16384 + ps * 16,                          \
                 GA + (size_t)(_r + 128) * K_TOT + (KOFF) + sl * 8);           \
} while (0)

// stage one B half-tile (H=0: rows 0-31,64-95,128-159,192-223; H=1: +32)
#define STAGE_B(H, LDSB, KOFF) do {                                            \
    int _r = rB + (H) * 32;                                                    \
    async_copy16((LDSB) + _r * 128 + ps * 16,                                  \
                 GB + (size_t)_r * K_TOT + (KOFF) + sl * 8);                   \
    async_copy16((LDSB) + _r * 128 + 16384 + ps * 16,                          \
                 GB + (size_t)(_r + 128) * K_TOT + (KOFF) + sl * 8);           \
} while (0)

__global__ __launch_bounds__(512) void gemm8_kernel(
    const __hip_bfloat16* __restrict__ X,
    const __hip_bfloat16* __restrict__ W,
    const float* __restrict__ scale,
    const __hip_bfloat16* __restrict__ loraB,
    const __hip_bfloat16* __restrict__ T,
    float* __restrict__ out)
{
    // 2 buffers x (A 256x64 + B 256x64) bf16 = 128 KiB
    __shared__ __align__(16) char lds[131072];
    char* const A0 = lds;
    char* const B0 = lds + 32768;
    char* const A1 = lds + 65536;
    char* const B1 = lds + 98304;

    // T1: bijective XCD chunking (512 wgs, 512%8==0)
    const int bid = blockIdx.x;
    const int swz = (bid & 7) * 64 + (bid >> 3);
    const int bm  = (swz & 31) * 256;   // 32 M-tiles
    const int bn  = (swz >> 5) * 256;   // 16 N-tiles

    const int tid  = threadIdx.x;
    const int lane = tid & 63;
    const int wid  = tid >> 6;
    const int wr   = wid >> 2;          // 2 wave-rows (128 out rows each)
    const int wc   = wid & 3;           // 4 wave-cols (64 out cols each)
    const int lrow = lane & 15;
    const int lk   = lane >> 4;
    const int q7   = lrow & 7;
    const int ps_k0 = lk ^ q7;          // physical 16B slot for ks=0
    const int ps_k1 = (4 + lk) ^ q7;    // physical 16B slot for ks=1

    // staging per-thread constants (issue0: region-rows 0-63; issue1 = +128)
    const int ps = tid & 7;             // physical slot this thread writes
    const int rr = tid >> 3;            // region-row 0..63
    const int sl = ps ^ (rr & 7);       // logical slot -> pre-swizzled source
    const int rA = rr;                              // A even-half row base
    const int rB = (rr >> 5) * 64 + (rr & 31);      // B even-half row base

    const __hip_bfloat16* GA = X + (size_t)bm * K_TOT;
    const __hip_bfloat16* GB = W + (size_t)bn * K_TOT;

    f32x4 acc[2][2][4][2] = {};         // [qi][qj][mf][nf]
    bf16x8 aq0[4][2], aq1[4][2], bq0[2][2], bq1[2][2];

    // prologue: tile0 {Ae,Be,Ao,Bo} + tile1 {Ae,Be,Ao} = 7 halves (14 ops)
    STAGE_A(0, A0, 0);  STAGE_B(0, B0, 0);
    STAGE_A(1, A0, 0);  STAGE_B(1, B0, 0);
    STAGE_A(0, A1, 64); STAGE_B(0, B1, 64);
    STAGE_A(1, A1, 64);
    WAITV(6);           // tile0 fully landed, 3 halves in flight
    BAR();

#pragma unroll 1
    for (int i = 0; i < 31; i++) {      // tiles 2i (buf0), 2i+1 (buf1)
        const int k0 = i * 128;
        // P1: Q00(t)
        READ_A(A0, 0, aq0); READ_B(B0, 0, bq0);
        STAGE_B(1, B1, k0 + 64);        // Bo(t+1)
        BAR(); WAITL();
        MFMA16(0, 0, aq0, bq0);
        BAR();
        // P2: Q10(t)
        READ_A(A0, 1, aq1);
        STAGE_A(0, A0, k0 + 128);       // Ae(t+2)
        BAR(); WAITL();
        MFMA16(1, 0, aq1, bq0);
        BAR();
        // P3: Q01(t)
        READ_B(B0, 1, bq1);
        STAGE_B(0, B0, k0 + 128);       // Be(t+2)
        BAR(); WAITL();
        MFMA16(0, 1, aq0, bq1);
        BAR();
        // P4: Q11(t)
        STAGE_A(1, A0, k0 + 128);       // Ao(t+2)
        WAITV(6); BAR();                // tile t+1 landed (3 halves in flight)
        MFMA16(1, 1, aq1, bq1);
        BAR();
        // P5: Q00(t+1)
        READ_A(A1, 0, aq0); READ_B(B1, 0, bq0);
        STAGE_B(1, B0, k0 + 128);       // Bo(t+2)
        BAR(); WAITL();
        MFMA16(0, 0, aq0, bq0);
        BAR();
        // P6: Q10(t+1)
        READ_A(A1, 1, aq1);
        STAGE_A(0, A1, k0 + 192);       // Ae(t+3)
        BAR(); WAITL();
        MFMA16(1, 0, aq1, bq0);
        BAR();
        // P7: Q01(t+1)
        READ_B(B1, 1, bq1);
        STAGE_B(0, B1, k0 + 192);       // Be(t+3)
        BAR(); WAITL();
        MFMA16(0, 1, aq0, bq1);
        BAR();
        // P8: Q11(t+1)
        STAGE_A(1, A1, k0 + 192);       // Ao(t+3)
        WAITV(6); BAR();                // tile t+2 landed
        MFMA16(1, 1, aq1, bq1);
        BAR();
    }
    // epilogue: tiles 62 (buf0) and 63 (buf1)
    {
        const int k0 = 31 * 128;
        READ_A(A0, 0, aq0); READ_B(B0, 0, bq0);
        STAGE_B(1, B1, k0 + 64);        // Bo(63) — last stage
        MFMA16(0, 0, aq0, bq0);
        READ_A(A0, 1, aq1);
        MFMA16(1, 0, aq1, bq0);
        READ_B(B0, 1, bq1);
        MFMA16(0, 1, aq0, bq1);
        MFMA16(1, 1, aq1, bq1);
        WAITV(0); BAR();                // tile 63 fully landed
        READ_A(A1, 0, aq0); READ_B(B1, 0, bq0);
        MFMA16(0, 0, aq0, bq0);
        READ_A(A1, 1, aq1);
        MFMA16(1, 0, aq1, bq0);
        READ_B(B1, 1, bq1);
        MFMA16(0, 1, aq0, bq1);
        MFMA16(1, 1, aq1, bq1);
    }

    // ---- epilogue: per-output-channel scale ----
    float scl[2][2];
#pragma unroll
    for (int qj = 0; qj < 2; qj++)
#pragma unroll
        for (int nf = 0; nf < 2; nf++)
            scl[qj][nf] = scale[bn + wc * 64 + qj * 32 + nf * 16 + lrow];
#pragma unroll
    for (int qi = 0; qi < 2; qi++)
#pragma unroll
        for (int qj = 0; qj < 2; qj++)
#pragma unroll
            for (int mf = 0; mf < 4; mf++)
#pragma unroll
                for (int nf = 0; nf < 2; nf++)
#pragma unroll
                    for (int r = 0; r < 4; r++)
                        acc[qi][qj][mf][nf][r] *= scl[qj][nf];

    // ---- fused LoRA: K=16 zero-padded to 32 ----
    bf16x8 zf = {};
    bf16x8 a2[2][4], b2[2][2];
#pragma unroll
    for (int qi = 0; qi < 2; qi++)
#pragma unroll
        for (int mf = 0; mf < 4; mf++)
            a2[qi][mf] = (lk < 2)
                ? *(const bf16x8*)(T + (size_t)(bm + wr * 128 + qi * 64 + mf * 16 + lrow) * RANK + lk * 8)
                : zf;
#pragma unroll
    for (int qj = 0; qj < 2; qj++)
#pragma unroll
        for (int nf = 0; nf < 2; nf++)
            b2[qj][nf] = (lk < 2)
                ? *(const bf16x8*)(loraB + (size_t)(bn + wc * 64 + qj * 32 + nf * 16 + lrow) * RANK + lk * 8)
                : zf;
#pragma unroll
    for (int qi = 0; qi < 2; qi++)
#pragma unroll
        for (int qj = 0; qj < 2; qj++)
#pragma unroll
            for (int mf = 0; mf < 4; mf++)
#pragma unroll
                for (int nf = 0; nf < 2; nf++)
                    acc[qi][qj][mf][nf] =
                        MFMA_16x16x32(a2[qi][mf], b2[qj][nf], acc[qi][qj][mf][nf]);

    // ---- store (C/D layout: col=lane&15, row=(lane>>4)*4+r) ----
#pragma unroll
    for (int qi = 0; qi < 2; qi++)
#pragma unroll
        for (int qj = 0; qj < 2; qj++)
#pragma unroll
            for (int mf = 0; mf < 4; mf++)
#pragma unroll
                for (int nf = 0; nf < 2; nf++)
#pragma unroll
                    for (int r = 0; r < 4; r++) {
                        int gm = bm + wr * 128 + qi * 64 + mf * 16 + lk * 4 + r;
                        int gn = bn + wc * 64 + qj * 32 + nf * 16 + lrow;
                        out[(size_t)gm * N_TOT + gn] = acc[qi][qj][mf][nf][r];
                    }
}

// ---------------------------------------------------------------------------
// Fallback (ws too small): naive fp32 correctness insurance (unchanged).
// ---------------------------------------------------------------------------
__global__ __launch_bounds__(256) void fallback_kernel(
    const float* __restrict__ X, const float* __restrict__ W,
    const float* __restrict__ scale, const float* __restrict__ lA,
    const float* __restrict__ lB, float* __restrict__ out)
{
    __shared__ float Tloc[64 * 16];
    const int bm = blockIdx.x * 64, bn = blockIdx.y * 64;

    for (int p = threadIdx.x; p < 1024; p += 256) {
        int m = p >> 4, r = p & 15;
        const float* xr = X + (size_t)(bm + m) * K_TOT;
        const float* ar = lA + (size_t)r * K_TOT;
        float s = 0.f;
        for (int k = 0; k < K_TOT; k++) s += xr[k] * ar[k];
        Tloc[m * 16 + r] = SCALING * s;
    }
    __syncthreads();

    const int m  = threadIdx.x >> 2;
    const int nq = threadIdx.x & 3;
    const float* xr = X + (size_t)(bm + m) * K_TOT;
    for (int jj = 0; jj < 16; jj++) {
        int n = nq * 16 + jj;
        const float* wr = W + (size_t)(bn + n) * K_TOT;
        float s = 0.f;
        for (int k = 0; k < K_TOT; k++) s += xr[k] * wr[k];
        float l = 0.f;
        for (int r = 0; r < 16; r++) l += Tloc[m * 16 + r] * lB[(size_t)(bn + n) * RANK + r];
        out[(size_t)(bm + m) * N_TOT + (bn + n)] = s * scale[bn + n] + l;
    }
}

// ---------------------------------------------------------------------------
extern "C" void kernel_launch(void* const* d_in, const int* in_sizes, int n_in,
                              void* d_out, int out_size, void* d_ws, size_t ws_size,
                              hipStream_t stream) {
    (void)in_sizes; (void)n_in; (void)out_size;
    const float* x      = (const float*)d_in[0];
    const float* signs  = (const float*)d_in[1];
    const float* scale  = (const float*)d_in[2];
    const float* lora_A = (const float*)d_in[3];
    const float* lora_B = (const float*)d_in[4];
    float* out = (float*)d_out;

    const size_t XB_OFF = 0;                         // 67108864 B
    const size_t WB_OFF = 67108864;                  // 33554432 B
    const size_t AB_OFF = 100663296;                 // 131072 B
    const size_t BB_OFF = 100794368;                 // 131072 B
    const size_t T_OFF  = 100925440;                 // 262144 B
    const size_t NEEDED = 101187584;

    if (ws_size >= NEEDED) {
        __hip_bfloat16* Xb = (__hip_bfloat16*)((char*)d_ws + XB_OFF);
        __hip_bfloat16* Wb = (__hip_bfloat16*)((char*)d_ws + WB_OFF);
        __hip_bfloat16* Ab = (__hip_bfloat16*)((char*)d_ws + AB_OFF);
        __hip_bfloat16* Bb = (__hip_bfloat16*)((char*)d_ws + BB_OFF);
        __hip_bfloat16* T  = (__hip_bfloat16*)((char*)d_ws + T_OFF);

        cvt_all_kernel<<<4096, 256, 0, stream>>>(x, signs, lora_A, lora_B, Xb, Wb, Ab, Bb);
        lora_t_kernel<<<M_TOT / 16, 256, 0, stream>>>(Xb, Ab, T);
        gemm8_kernel<<<dim3(512), dim3(512), 0, stream>>>(Xb, Wb, scale, Bb, T, out);
    } else {
        dim3 grid(M_TOT / 64, N_TOT / 64);
        fallback_kernel<<<grid, 256, 0, stream>>>(x, signs, scale, lora_A, lora_B, out);
    }
}